// Round 1
// baseline (2162.089 us; speedup 1.0000x reference)
//
// MoE (top-2 of 8) + shared SwiGLU FFN — MI355X bf16-MFMA implementation.
// Round 1: sparse dispatch (exact vs reference since w_full==0 off the top-2),
// 128x128x64-tile MFMA GEMMs with global_load_lds(16B) staging + XOR swizzle.
// ws budget ~387 MB: bf16 copies of x + transposed expert weights + shared
// weights, grouped hidden buffer, router metadata.
#include <hip/hip_runtime.h>
#include <hip/hip_bf16.h>
#include <stdint.h>

#define TT 8192
#define DMODEL 4096
#define NE 8
#define HE 1024
#define SHH 2048

typedef __bf16 bf16x8 __attribute__((ext_vector_type(8)));
typedef float f32x4 __attribute__((ext_vector_type(4)));

// global -> LDS async copy, 16B per lane; LDS dest is wave-uniform base + lane*16
#define GLOAD16(gp, lp) __builtin_amdgcn_global_load_lds( \
    (__attribute__((address_space(1))) void*)(void*)(gp), \
    (__attribute__((address_space(3))) void*)(lp), 16, 0, 0)

// ---------------- fp32 -> bf16 convert (vectorized, grid-stride) ----------------
__global__ __launch_bounds__(256) void k_convert(const float* __restrict__ in,
                                                 __bf16* __restrict__ out, long n) {
  long i = (long)blockIdx.x * blockDim.x + threadIdx.x;
  long stride = (long)gridDim.x * blockDim.x;
  for (long j = i * 8; j < n; j += stride * 8) {
    float4 a = *(const float4*)(in + j);
    float4 b = *(const float4*)(in + j + 4);
    alignas(16) __bf16 o[8] = {(__bf16)a.x, (__bf16)a.y, (__bf16)a.z, (__bf16)a.w,
                               (__bf16)b.x, (__bf16)b.y, (__bf16)b.z, (__bf16)b.w};
    *reinterpret_cast<bf16x8*>(out + j) = *reinterpret_cast<const bf16x8*>(o);
  }
}

// ------------- transpose + convert: in [z][R][C] f32 -> out [z][C][R] bf16 -------------
__global__ __launch_bounds__(256) void k_transpose(const float* __restrict__ in,
                                                   __bf16* __restrict__ out, int R, int C) {
  __shared__ float tile[64][65];
  size_t zo = (size_t)blockIdx.z * R * C;
  int r0 = blockIdx.y * 64, c0 = blockIdx.x * 64;
  int t = threadIdx.x;
  int lr = t >> 4;          // 0..15
  int lc = (t & 15) * 4;    // 0..60
#pragma unroll
  for (int i = 0; i < 4; i++) {
    int r = lr + i * 16;
    float4 v = *(const float4*)(in + zo + (size_t)(r0 + r) * C + c0 + lc);
    tile[r][lc] = v.x; tile[r][lc + 1] = v.y; tile[r][lc + 2] = v.z; tile[r][lc + 3] = v.w;
  }
  __syncthreads();
#pragma unroll
  for (int i = 0; i < 4; i++) {
    int c = lr + i * 16;  // input col == output row
    alignas(8) __bf16 o[4];
    o[0] = (__bf16)tile[lc + 0][c]; o[1] = (__bf16)tile[lc + 1][c];
    o[2] = (__bf16)tile[lc + 2][c]; o[3] = (__bf16)tile[lc + 3][c];
    *reinterpret_cast<uint2*>(out + zo + (size_t)(c0 + c) * R + r0 + lc) =
        *reinterpret_cast<const uint2*>(o);
  }
}

// ---------------- router: fp32 logits, top-2, softmax over the 2 ----------------
__global__ __launch_bounds__(256) void k_router(const float* __restrict__ x,
                                                const float* __restrict__ rw,
                                                int* __restrict__ tope, float* __restrict__ tops,
                                                int* __restrict__ counts) {
  int wave = threadIdx.x >> 6, lane = threadIdx.x & 63;
  int t = blockIdx.x * 4 + wave;
  float acc[NE];
#pragma unroll
  for (int e = 0; e < NE; e++) acc[e] = 0.f;
  const float* xr = x + (size_t)t * DMODEL;
  for (int k = lane * 4; k < DMODEL; k += 64 * 4) {
    float4 xv = *(const float4*)(xr + k);
#pragma unroll
    for (int e = 0; e < NE; e++) {
      float4 wv = *(const float4*)(rw + (size_t)e * DMODEL + k);
      acc[e] += xv.x * wv.x + xv.y * wv.y + xv.z * wv.z + xv.w * wv.w;
    }
  }
#pragma unroll
  for (int e = 0; e < NE; e++) {
    float v = acc[e];
#pragma unroll
    for (int off = 32; off > 0; off >>= 1) v += __shfl_xor(v, off);
    acc[e] = v;
  }
  if (lane == 0) {
    int i0 = -1, i1 = -1; float v0 = -1e30f, v1 = -1e30f;
#pragma unroll
    for (int e = 0; e < NE; e++) {
      float v = acc[e];
      if (v > v0) { v1 = v0; i1 = i0; v0 = v; i0 = e; }
      else if (v > v1) { v1 = v; i1 = e; }
    }
    float ex1 = __expf(v1 - v0);
    float s = 1.f / (1.f + ex1);
    tope[t * 2] = i0; tope[t * 2 + 1] = i1;
    tops[t * 2] = s;  tops[t * 2 + 1] = ex1 * s;
    atomicAdd(&counts[i0], 1); atomicAdd(&counts[i1], 1);
  }
}

__global__ void k_offsets(const int* __restrict__ counts, int* __restrict__ offsets,
                          int* __restrict__ cursors) {
  if (threadIdx.x == 0) {
    int s = 0;
    for (int e = 0; e < NE; e++) { offsets[e] = s; s += counts[e]; }
  }
  if (threadIdx.x < NE) cursors[threadIdx.x] = 0;
}

__global__ __launch_bounds__(256) void k_scatter(const int* __restrict__ tope,
                                                 const float* __restrict__ tops,
                                                 const int* __restrict__ offsets,
                                                 int* __restrict__ cursors,
                                                 int* __restrict__ rows, float* __restrict__ wts) {
  int t = blockIdx.x * 256 + threadIdx.x;
  if (t >= TT) return;
#pragma unroll
  for (int j = 0; j < 2; j++) {
    int e = tope[t * 2 + j]; float s = tops[t * 2 + j];
    int p = atomicAdd(&cursors[e], 1);
    int g = offsets[e] + p;
    rows[g] = t; wts[g] = s;
  }
}

// ------------- fused gate/up GEMM + SwiGLU epilogue -------------
// A: bf16 [?, Kd] (gathered by rows[] if non-null); Bg/Bu: bf16 [z][N][Kd] (n-major);
// Cout: bf16, row (off+grow), stride N. 128x128 tile, BK=64, 4 waves.
__global__ __launch_bounds__(256, 2) void k_gemm_gateup(
    const __bf16* __restrict__ A, const __bf16* __restrict__ Bg,
    const __bf16* __restrict__ Bu, __bf16* __restrict__ Cout,
    const int* __restrict__ rows, const int* __restrict__ counts,
    const int* __restrict__ offsets, int N, int Kd) {
  const int z = blockIdx.z;
  const int cnt = counts ? counts[z] : TT;
  const int tile_m = blockIdx.x;
  if (tile_m * 128 >= cnt) return;
  const int off = offsets ? offsets[z] : 0;
  const int tile_n = blockIdx.y;
  const __bf16* Bge = Bg + (size_t)z * N * Kd;
  const __bf16* Bue = Bu + (size_t)z * N * Kd;

  __shared__ __bf16 lA[128 * 64];
  __shared__ __bf16 lBg[128 * 64];
  __shared__ __bf16 lBu[128 * 64];

  const int tid = threadIdx.x;
  const int w = tid >> 6, lane = tid & 63;
  const int srow = lane >> 3;               // dest row within 8-row issue group
  const int chunk = (lane & 7) ^ srow;      // pre-swizzled global 16B-chunk

  const __bf16* pa[4]; const __bf16* pg[4]; const __bf16* pu[4];
#pragma unroll
  for (int i = 0; i < 4; i++) {
    int rl = w * 32 + i * 8 + srow;
    int grow = tile_m * 128 + rl;
    int tok;
    if (rows) tok = (grow < cnt) ? rows[off + grow] : rows[off];
    else      tok = grow;
    pa[i] = A + (size_t)tok * Kd + chunk * 8;
    int gn = tile_n * 128 + rl;
    pg[i] = Bge + (size_t)gn * Kd + chunk * 8;
    pu[i] = Bue + (size_t)gn * Kd + chunk * 8;
  }

  f32x4 accg[4][4], accu[4][4];
#pragma unroll
  for (int a = 0; a < 4; a++)
#pragma unroll
    for (int b = 0; b < 4; b++) { accg[a][b] = 0.f; accu[a][b] = 0.f; }

  const int wm = (w >> 1) * 64, wn = (w & 1) * 64;
  const int lm = lane & 15, lk = lane >> 4;

  for (int ks = 0; ks < Kd; ks += 64) {
#pragma unroll
    for (int i = 0; i < 4; i++) {
      GLOAD16(pa[i], &lA[(w * 32 + i * 8) * 64]);
      GLOAD16(pg[i], &lBg[(w * 32 + i * 8) * 64]);
      GLOAD16(pu[i], &lBu[(w * 32 + i * 8) * 64]);
      pa[i] += 64; pg[i] += 64; pu[i] += 64;
    }
    __syncthreads();
#pragma unroll
    for (int kk = 0; kk < 2; kk++) {
      bf16x8 af[4], bgf[4], buf_[4];
#pragma unroll
      for (int f = 0; f < 4; f++) {
        int ra = wm + f * 16 + lm;
        int ca = (kk * 4 + lk) ^ (ra & 7);
        af[f] = *(const bf16x8*)&lA[ra * 64 + ca * 8];
        int rb = wn + f * 16 + lm;
        int cb = (kk * 4 + lk) ^ (rb & 7);
        bgf[f]  = *(const bf16x8*)&lBg[rb * 64 + cb * 8];
        buf_[f] = *(const bf16x8*)&lBu[rb * 64 + cb * 8];
      }
#pragma unroll
      for (int fm = 0; fm < 4; fm++)
#pragma unroll
        for (int fn = 0; fn < 4; fn++) {
          accg[fm][fn] = __builtin_amdgcn_mfma_f32_16x16x32_bf16(af[fm], bgf[fn], accg[fm][fn], 0, 0, 0);
          accu[fm][fn] = __builtin_amdgcn_mfma_f32_16x16x32_bf16(af[fm], buf_[fn], accu[fm][fn], 0, 0, 0);
        }
    }
    __syncthreads();
  }
  // epilogue: C/D layout col=lane&15, row=(lane>>4)*4+reg (m89-verified)
#pragma unroll
  for (int fm = 0; fm < 4; fm++) {
#pragma unroll
    for (int r = 0; r < 4; r++) {
      int grow = tile_m * 128 + wm + fm * 16 + lk * 4 + r;
      if (!counts || grow < cnt) {
        size_t rowoff = (size_t)(off + grow) * N;
#pragma unroll
        for (int fn = 0; fn < 4; fn++) {
          int col = tile_n * 128 + wn + fn * 16 + lm;
          float g = accg[fm][fn][r], u = accu[fm][fn][r];
          float h = g / (1.f + __expf(-g)) * u;   // silu(g)*u
          Cout[rowoff + col] = (__bf16)h;
        }
      }
    }
  }
}

// ------------- down-proj GEMM; MOE=1: weighted atomicAdd scatter, MOE=0: += -------------
template <int MOE>
__global__ __launch_bounds__(256, 2) void k_gemm_down(
    const __bf16* __restrict__ A, const __bf16* __restrict__ B,
    float* __restrict__ out, const int* __restrict__ rows,
    const float* __restrict__ wts, const int* __restrict__ counts,
    const int* __restrict__ offsets, int Kd) {
  const int z = blockIdx.z;
  const int cnt = MOE ? counts[z] : TT;
  const int tile_m = blockIdx.x;
  if (tile_m * 128 >= cnt) return;
  const int off = MOE ? offsets[z] : 0;
  const int tile_n = blockIdx.y;
  const __bf16* Be = B + (size_t)z * DMODEL * Kd;

  __shared__ __bf16 lA[128 * 64];
  __shared__ __bf16 lB[128 * 64];

  const int tid = threadIdx.x, w = tid >> 6, lane = tid & 63;
  const int srow = lane >> 3, chunk = (lane & 7) ^ srow;

  const __bf16* pa[4]; const __bf16* pb[4];
#pragma unroll
  for (int i = 0; i < 4; i++) {
    int rl = w * 32 + i * 8 + srow;
    int grow = tile_m * 128 + rl;
    pa[i] = A + (size_t)(off + grow) * Kd + chunk * 8;  // grouped rows are contiguous
    int gn = tile_n * 128 + rl;
    pb[i] = Be + (size_t)gn * Kd + chunk * 8;
  }

  f32x4 acc[4][4];
#pragma unroll
  for (int a = 0; a < 4; a++)
#pragma unroll
    for (int b = 0; b < 4; b++) acc[a][b] = 0.f;

  const int wm = (w >> 1) * 64, wn = (w & 1) * 64;
  const int lm = lane & 15, lk = lane >> 4;

  for (int ks = 0; ks < Kd; ks += 64) {
#pragma unroll
    for (int i = 0; i < 4; i++) {
      GLOAD16(pa[i], &lA[(w * 32 + i * 8) * 64]);
      GLOAD16(pb[i], &lB[(w * 32 + i * 8) * 64]);
      pa[i] += 64; pb[i] += 64;
    }
    __syncthreads();
#pragma unroll
    for (int kk = 0; kk < 2; kk++) {
      bf16x8 af[4], bf_[4];
#pragma unroll
      for (int f = 0; f < 4; f++) {
        int ra = wm + f * 16 + lm;
        int ca = (kk * 4 + lk) ^ (ra & 7);
        af[f] = *(const bf16x8*)&lA[ra * 64 + ca * 8];
        int rb = wn + f * 16 + lm;
        int cb = (kk * 4 + lk) ^ (rb & 7);
        bf_[f] = *(const bf16x8*)&lB[rb * 64 + cb * 8];
      }
#pragma unroll
      for (int fm = 0; fm < 4; fm++)
#pragma unroll
        for (int fn = 0; fn < 4; fn++)
          acc[fm][fn] = __builtin_amdgcn_mfma_f32_16x16x32_bf16(af[fm], bf_[fn], acc[fm][fn], 0, 0, 0);
    }
    __syncthreads();
  }
#pragma unroll
  for (int fm = 0; fm < 4; fm++) {
#pragma unroll
    for (int r = 0; r < 4; r++) {
      int grow = tile_m * 128 + wm + fm * 16 + lk * 4 + r;
      if (grow < cnt) {
        if (MOE) {
          int tok = rows[off + grow];
          float wgt = wts[off + grow];
#pragma unroll
          for (int fn = 0; fn < 4; fn++) {
            int col = tile_n * 128 + wn + fn * 16 + lm;
            atomicAdd(&out[(size_t)tok * DMODEL + col], wgt * acc[fm][fn][r]);
          }
        } else {
#pragma unroll
          for (int fn = 0; fn < 4; fn++) {
            int col = tile_n * 128 + wn + fn * 16 + lm;
            size_t idx = (size_t)grow * DMODEL + col;
            out[idx] += acc[fm][fn][r];
          }
        }
      }
    }
  }
}

extern "C" void kernel_launch(void* const* d_in, const int* in_sizes, int n_in,
                              void* d_out, int out_size, void* d_ws, size_t ws_size,
                              hipStream_t stream) {
  const float* x  = (const float*)d_in[0];
  const float* rw = (const float*)d_in[1];
  const float* gp = (const float*)d_in[2];
  const float* up = (const float*)d_in[3];
  const float* dp = (const float*)d_in[4];
  const float* w1 = (const float*)d_in[5];
  const float* w2 = (const float*)d_in[6];   // NOTE: dict order is w1, w2, w3
  const float* w3 = (const float*)d_in[7];
  float* out = (float*)d_out;

  char* ws = (char*)d_ws;
  size_t o = 0;
  auto alloc = [&](size_t b) { size_t r = o; o += (b + 255) & ~(size_t)255; return r; };
  __bf16* xb     = (__bf16*)(ws + alloc((size_t)TT * DMODEL * 2));
  __bf16* gt     = (__bf16*)(ws + alloc((size_t)NE * HE * DMODEL * 2));  // [E][H][D]
  __bf16* ut     = (__bf16*)(ws + alloc((size_t)NE * HE * DMODEL * 2));
  __bf16* dt     = (__bf16*)(ws + alloc((size_t)NE * DMODEL * HE * 2));  // [E][D][H]
  __bf16* w1b    = (__bf16*)(ws + alloc((size_t)SHH * DMODEL * 2));
  __bf16* w3b    = (__bf16*)(ws + alloc((size_t)SHH * DMODEL * 2));
  __bf16* w2b    = (__bf16*)(ws + alloc((size_t)DMODEL * SHH * 2));
  __bf16* hidden = (__bf16*)(ws + alloc((size_t)(2 * TT + 128) * HE * 2));
  __bf16* hs     = (__bf16*)(ws + alloc((size_t)TT * SHH * 2));
  int*   rows    = (int*)(ws + alloc((2 * TT + 128) * 4));
  float* wts     = (float*)(ws + alloc((2 * TT + 128) * 4));
  int*   tope    = (int*)(ws + alloc(TT * 2 * 4));
  float* tops    = (float*)(ws + alloc(TT * 2 * 4));
  int*   ctrl    = (int*)(ws + alloc(256));  // counts[8] | cursors[8] | offsets[8]
  int* counts = ctrl, *cursors = ctrl + 8, *offs = ctrl + 16;

  hipMemsetAsync(ctrl, 0, 64, stream);
  hipMemsetAsync(out, 0, (size_t)TT * DMODEL * 4, stream);

  k_convert<<<2048, 256, 0, stream>>>(x, xb, (long)TT * DMODEL);
  k_convert<<<512, 256, 0, stream>>>(w1, w1b, (long)SHH * DMODEL);
  k_convert<<<512, 256, 0, stream>>>(w3, w3b, (long)SHH * DMODEL);
  k_convert<<<512, 256, 0, stream>>>(w2, w2b, (long)DMODEL * SHH);

  dim3 tg(HE / 64, DMODEL / 64, NE);     // gate/up: [D][H] -> [H][D]
  k_transpose<<<tg, 256, 0, stream>>>(gp, gt, DMODEL, HE);
  k_transpose<<<tg, 256, 0, stream>>>(up, ut, DMODEL, HE);
  dim3 td(DMODEL / 64, HE / 64, NE);     // down: [H][D] -> [D][H]
  k_transpose<<<td, 256, 0, stream>>>(dp, dt, HE, DMODEL);

  k_router<<<TT / 4, 256, 0, stream>>>(x, rw, tope, tops, counts);
  k_offsets<<<1, 64, 0, stream>>>(counts, offs, cursors);
  k_scatter<<<TT / 256, 256, 0, stream>>>(tope, tops, offs, cursors, rows, wts);

  k_gemm_gateup<<<dim3(64, HE / 128, NE), 256, 0, stream>>>(
      xb, gt, ut, hidden, rows, counts, offs, HE, DMODEL);
  k_gemm_gateup<<<dim3(64, SHH / 128, 1), 256, 0, stream>>>(
      xb, w1b, w3b, hs, nullptr, nullptr, nullptr, SHH, DMODEL);
  k_gemm_down<1><<<dim3(64, DMODEL / 128, NE), 256, 0, stream>>>(
      hidden, dt, out, rows, wts, counts, offs, HE);
  k_gemm_down<0><<<dim3(64, DMODEL / 128, 1), 256, 0, stream>>>(
      hs, w2b, out, nullptr, nullptr, nullptr, nullptr, SHH);
}